// Round 5
// baseline (288.734 us; speedup 1.0000x reference)
//
#include <hip/hip_runtime.h>
#include <hip/hip_fp16.h>

// TriMipEncoding: N pts, 3 planes (512^2, 16 ch), 8 mip levels, trilinear sample.
//
// R4 evidence: cost = unique-cache-line requests per gather instruction
// (LDS-staging of small levels was a no-op; FETCH-independent). R5: counting
// sort by key=[l0:3][morton3d:12] so each wave's lanes tap neighboring
// texels at one level -> line-requests merge. L0 sampled from fm (fp32,
// exact); levels 1..7 as fp16 in ws.
//
// ws layout (bytes), needs 19,005,440 + slack:
//   [0, 8388608)            fp16 pyramid levels 1..7: 3 planes x 87376 texels x 32 B
//   [8388608, +16N)         spos: sorted float4 {x,y,z,lvl}
//   [+16N, +4N)             sidx: sorted original point index
//   [.., +131072)           hist: 32768 bins
// Fallback (small ws): fp32 pyramid path (R2-style).

typedef float        f4v   __attribute__((ext_vector_type(4)));
typedef unsigned int u32x2 __attribute__((ext_vector_type(2)));

#define FM_PLANE_STRIDE (262144 * 16)   // floats per plane in fm
#define PW_STRIDE_H (87376 * 16)        // halfs per plane, fp16 pyramid (levels 1..7)
#define PYR_BYTES 8388608ull
#define WS_PLANE_STRIDE (87376 * 16)    // floats per plane, fp32 fallback pyramid
#define NBINS 32768

__device__ __forceinline__ unsigned lvl_off_ws(int l) {  // texel offset, levels 1..7
    const int sz = 512 >> l;
    return (262144u - ((unsigned)(sz * sz) << 2)) / 3u;
}

__device__ __forceinline__ f4v ld4(const float* p) {
    return *reinterpret_cast<const f4v*>(p);
}
__device__ __forceinline__ f4v ld4nt(const float* p) {
    return __builtin_nontemporal_load(reinterpret_cast<const f4v*>(p));
}
__device__ __forceinline__ void st4(float* p, f4v v) {
    *reinterpret_cast<f4v*>(p) = v;
}
__device__ __forceinline__ void st4nt(float* p, f4v v) {
    __builtin_nontemporal_store(v, reinterpret_cast<f4v*>(p));
}
__device__ __forceinline__ f4v ldraw_h(const __half* p) {   // 8 halfs as raw f4v
    return *reinterpret_cast<const f4v*>(p);
}
__device__ __forceinline__ u32x2 pack4(f4v v) {             // 4 floats -> 4 halfs
    __half2 lo = __floats2half2_rn(v.x, v.y);
    __half2 hi = __floats2half2_rn(v.z, v.w);
    u32x2 r;
    r.x = *reinterpret_cast<unsigned*>(&lo);
    r.y = *reinterpret_cast<unsigned*>(&hi);
    return r;
}
__device__ __forceinline__ f4v h4f(const __half* p) {       // 4 halfs -> 4 floats
    u32x2 u = *reinterpret_cast<const u32x2*>(p);
    unsigned a0 = u.x, a1 = u.y;
    __half2 lo = *reinterpret_cast<__half2*>(&a0);
    __half2 hi = *reinterpret_cast<__half2*>(&a1);
    float2 flo = __half22float2(lo), fhi = __half22float2(hi);
    f4v r; r.x = flo.x; r.y = flo.y; r.z = fhi.x; r.w = fhi.y;
    return r;
}
__device__ __forceinline__ float2 up2(float rawcomp) {      // 2 packed halfs -> 2 floats
    unsigned u = __float_as_uint(rawcomp);
    __half2 hh = *reinterpret_cast<__half2*>(&u);
    return __half22float2(hh);
}
__device__ __forceinline__ unsigned part1by2(unsigned v) {  // spread low bits by 3
    v = (v | (v << 16)) & 0x030000FFu;
    v = (v | (v << 8))  & 0x0300F00Fu;
    v = (v | (v << 4))  & 0x030C30C3u;
    v = (v | (v << 2))  & 0x09249249u;
    return v;
}
__device__ __forceinline__ unsigned point_key(float x, float y, float z, float lv) {
    int xi = min(max((int)(x * 16.f), 0), 15);
    int yi = min(max((int)(y * 16.f), 0), 15);
    int zi = min(max((int)(z * 16.f), 0), 15);
    int l0 = (int)lv;                       // lv pre-clamped to [0,7]
    unsigned m = part1by2((unsigned)xi) | (part1by2((unsigned)yi) << 1)
               | (part1by2((unsigned)zi) << 2);
    return ((unsigned)l0 << 12) | m;
}

// ---------------- pyramid (fp16 levels 1..7) ----------------

// fm (fp32) -> L1 fp16. Thread per (L1 texel, quad q); grid (1024, 3).
__global__ __launch_bounds__(256) void mip_l1_h(
    const float* __restrict__ fm, __half* __restrict__ pyr)
{
    int t = blockIdx.x * 256 + threadIdx.x;
    const int p = blockIdx.y;
    const int q = t & 3, idx = t >> 2;
    const int y = idx >> 8, x = idx & 255;
    const float* sp = fm + (size_t)p * FM_PLANE_STRIDE
                         + ((size_t)(2 * y) * 512 + 2 * x) * 16 + q * 4;
    f4v a = ld4nt(sp);
    f4v b = ld4nt(sp + 16);
    f4v c = ld4nt(sp + 512 * 16);
    f4v d = ld4nt(sp + 512 * 16 + 16);
    f4v m = (a + b + c + d) * 0.25f;
    __half* L1 = pyr + (size_t)p * PW_STRIDE_H;
    *reinterpret_cast<u32x2*>(L1 + ((size_t)y * 256 + x) * 16 + q * 4) = pack4(m);
}

// Fused L2..L7 (fp16). Block = (32x32 L2 tile, quad q, plane p); grid (16,4,3).
__global__ __launch_bounds__(256) void mip_tail_h(__half* __restrict__ pyr)
{
    const int tile = blockIdx.x;
    const int q    = blockIdx.y;
    const int p    = blockIdx.z;
    const int ty = tile >> 2, tx = tile & 3;
    const int tid = threadIdx.x;

    __shared__ f4v A[32 * 32];
    __shared__ f4v B[16 * 16];

    __half* plane = pyr + (size_t)p * PW_STRIDE_H;
    const __half* L1 = plane;
    __half* L2 = plane + (size_t)65536 * 16;
    __half* L3 = plane + (size_t)81920 * 16;
    __half* L4 = plane + (size_t)86016 * 16;
    __half* L5 = plane + (size_t)87040 * 16;
    __half* L6 = plane + (size_t)87296 * 16;
    __half* L7 = plane + (size_t)87360 * 16;

    #pragma unroll
    for (int k = 0; k < 4; ++k) {
        int li = tid + k * 256;
        int ly = li >> 5, lx = li & 31;
        int gy = ty * 32 + ly, gx = tx * 32 + lx;
        const __half* sp = L1 + ((size_t)(2 * gy) * 256 + 2 * gx) * 16 + q * 4;
        f4v r = (h4f(sp) + h4f(sp + 16) + h4f(sp + 256 * 16) + h4f(sp + 256 * 16 + 16)) * 0.25f;
        A[li] = r;
        *reinterpret_cast<u32x2*>(L2 + ((size_t)gy * 128 + gx) * 16 + q * 4) = pack4(r);
    }
    __syncthreads();

    {   // L3: 16x16
        int ly = tid >> 4, lx = tid & 15;
        f4v r = (A[(2 * ly) * 32 + 2 * lx]     + A[(2 * ly) * 32 + 2 * lx + 1] +
                 A[(2 * ly + 1) * 32 + 2 * lx] + A[(2 * ly + 1) * 32 + 2 * lx + 1]) * 0.25f;
        B[tid] = r;
        *reinterpret_cast<u32x2*>(L3 + ((size_t)(ty * 16 + ly) * 64 + tx * 16 + lx) * 16 + q * 4) = pack4(r);
    }
    __syncthreads();

    if (tid < 64) {   // L4: 8x8
        int ly = tid >> 3, lx = tid & 7;
        f4v r = (B[(2 * ly) * 16 + 2 * lx]     + B[(2 * ly) * 16 + 2 * lx + 1] +
                 B[(2 * ly + 1) * 16 + 2 * lx] + B[(2 * ly + 1) * 16 + 2 * lx + 1]) * 0.25f;
        A[tid] = r;
        *reinterpret_cast<u32x2*>(L4 + ((size_t)(ty * 8 + ly) * 32 + tx * 8 + lx) * 16 + q * 4) = pack4(r);
    }
    __syncthreads();

    if (tid < 16) {   // L5: 4x4
        int ly = tid >> 2, lx = tid & 3;
        f4v r = (A[(2 * ly) * 8 + 2 * lx]     + A[(2 * ly) * 8 + 2 * lx + 1] +
                 A[(2 * ly + 1) * 8 + 2 * lx] + A[(2 * ly + 1) * 8 + 2 * lx + 1]) * 0.25f;
        B[tid] = r;
        *reinterpret_cast<u32x2*>(L5 + ((size_t)(ty * 4 + ly) * 16 + tx * 4 + lx) * 16 + q * 4) = pack4(r);
    }
    __syncthreads();

    if (tid < 4) {    // L6: 2x2
        int ly = tid >> 1, lx = tid & 1;
        f4v r = (B[(2 * ly) * 4 + 2 * lx]     + B[(2 * ly) * 4 + 2 * lx + 1] +
                 B[(2 * ly + 1) * 4 + 2 * lx] + B[(2 * ly + 1) * 4 + 2 * lx + 1]) * 0.25f;
        A[tid] = r;
        *reinterpret_cast<u32x2*>(L6 + ((size_t)(ty * 2 + ly) * 8 + tx * 2 + lx) * 16 + q * 4) = pack4(r);
    }
    __syncthreads();

    if (tid == 0) {   // L7: 1 texel
        f4v r = (A[0] + A[1] + A[2] + A[3]) * 0.25f;
        *reinterpret_cast<u32x2*>(L7 + ((size_t)ty * 4 + tx) * 16 + q * 4) = pack4(r);
    }
}

// ---------------- sort pipeline ----------------

__global__ __launch_bounds__(256) void hist_build(
    const float* __restrict__ xyz, const float* __restrict__ level,
    unsigned* __restrict__ hist, int N)
{
    int n = blockIdx.x * 256 + threadIdx.x;
    if (n >= N) return;
    float x = xyz[n * 3], y = xyz[n * 3 + 1], z = xyz[n * 3 + 2];
    float lv = fminf(fmaxf(level[n], 0.f), 7.f);
    atomicAdd(&hist[point_key(x, y, z, lv)], 1u);
}

// Exclusive scan of 32768 bins. One block, 1024 threads, 32 bins/thread.
__global__ __launch_bounds__(1024) void scan_hist(unsigned* __restrict__ hist)
{
    __shared__ unsigned s[1024];
    const unsigned tid = threadIdx.x;
    const unsigned base = tid * 32;
    unsigned sum = 0;
    #pragma unroll
    for (int k = 0; k < 32; ++k) sum += hist[base + k];
    s[tid] = sum;
    __syncthreads();
    for (unsigned off = 1; off < 1024; off <<= 1) {        // Hillis-Steele inclusive
        unsigned v = (tid >= off) ? s[tid - off] : 0u;
        __syncthreads();
        s[tid] += v;
        __syncthreads();
    }
    unsigned run = s[tid] - sum;                            // exclusive offset
    #pragma unroll
    for (int k = 0; k < 32; ++k) {
        unsigned h = hist[base + k];
        hist[base + k] = run;
        run += h;
    }
}

__global__ __launch_bounds__(256) void scatter_pts(
    const float* __restrict__ xyz, const float* __restrict__ level,
    unsigned* __restrict__ hist, float* __restrict__ spos,
    unsigned* __restrict__ sidx, int N)
{
    int n = blockIdx.x * 256 + threadIdx.x;
    if (n >= N) return;
    float x = xyz[n * 3], y = xyz[n * 3 + 1], z = xyz[n * 3 + 2];
    float lv = fminf(fmaxf(level[n], 0.f), 7.f);
    unsigned pos = atomicAdd(&hist[point_key(x, y, z, lv)], 1u);
    f4v v; v.x = x; v.y = y; v.z = z; v.w = lv;
    st4nt(spos + (size_t)pos * 4, v);
    __builtin_nontemporal_store(n, (int*)&sidx[pos]);
}

// ---------------- sorted sampler ----------------

// 8-channel half-texel tap, level 0 from fm (fp32, 2x16B loads per tap).
__device__ __forceinline__ void bilerp_l0(
    const float* __restrict__ fm, int p, float u, float v, int h, float* o)
{
    float px = u * 512.f - 0.5f;
    float py = v * 512.f - 0.5f;
    float xf = floorf(px), yf = floorf(py);
    float fx = px - xf, fy = py - yf;
    int xi = (int)xf, yi = (int)yf;
    int xa = min(max(xi, 0), 511);
    int xb = min(xi + 1, 511);
    int ya = min(max(yi, 0), 511);
    int yb = min(yi + 1, 511);
    const float* base = fm + (size_t)p * FM_PLANE_STRIDE + h * 8;
    const float* p00 = base + ((size_t)ya * 512 + xa) * 16;
    const float* p01 = base + ((size_t)ya * 512 + xb) * 16;
    const float* p10 = base + ((size_t)yb * 512 + xa) * 16;
    const float* p11 = base + ((size_t)yb * 512 + xb) * 16;
    f4v a0 = ld4(p00), a1 = ld4(p00 + 4);
    f4v b0 = ld4(p01), b1 = ld4(p01 + 4);
    f4v c0 = ld4(p10), c1 = ld4(p10 + 4);
    f4v d0 = ld4(p11), d1 = ld4(p11 + 4);
    float gx = 1.f - fx, gy = 1.f - fy;
    float w00 = gx * gy, w01 = fx * gy, w10 = gx * fy, w11 = fx * fy;
    f4v lo = a0 * w00 + b0 * w01 + c0 * w10 + d0 * w11;
    f4v hi = a1 * w00 + b1 * w01 + c1 * w10 + d1 * w11;
    #pragma unroll
    for (int i = 0; i < 4; ++i) { o[i] = lo[i]; o[4 + i] = hi[i]; }
}

// 8-channel half-texel tap, levels 1..7 from fp16 pyramid (4x16B loads).
__device__ __forceinline__ void bilerp_h(
    const __half* __restrict__ pyr, int p, int l, float u, float v, int h, float* o)
{
    const int sz = 512 >> l;
    const float fsz = (float)sz;
    float px = u * fsz - 0.5f;
    float py = v * fsz - 0.5f;
    float xf = floorf(px), yf = floorf(py);
    float fx = px - xf, fy = py - yf;
    int xi = (int)xf, yi = (int)yf;
    int xa = min(max(xi, 0), sz - 1);
    int xb = min(xi + 1, sz - 1);
    int ya = min(max(yi, 0), sz - 1);
    int yb = min(yi + 1, sz - 1);
    const __half* base = pyr + (size_t)p * PW_STRIDE_H + (size_t)lvl_off_ws(l) * 16 + h * 8;
    const __half* r0 = base + (size_t)(ya * sz) * 16;
    const __half* r1 = base + (size_t)(yb * sz) * 16;
    f4v q00 = ldraw_h(r0 + (size_t)xa * 16);
    f4v q01 = ldraw_h(r0 + (size_t)xb * 16);
    f4v q10 = ldraw_h(r1 + (size_t)xa * 16);
    f4v q11 = ldraw_h(r1 + (size_t)xb * 16);
    float gx = 1.f - fx, gy = 1.f - fy;
    float w00 = gx * gy, w01 = fx * gy, w10 = gx * fy, w11 = fx * fy;
    #pragma unroll
    for (int i = 0; i < 4; ++i) {
        float2 a = up2(q00[i]), b = up2(q01[i]), c = up2(q10[i]), d = up2(q11[i]);
        o[2 * i]     = a.x * w00 + b.x * w01 + c.x * w10 + d.x * w11;
        o[2 * i + 1] = a.y * w00 + b.y * w01 + c.y * w10 + d.y * w11;
    }
}

// Plane-major sorted sampler: blockIdx.y = plane; tl in [0, 2N);
// rank = tl>>1 (sorted order), h = tl&1. Wave = 32 same-bucket points.
__global__ __launch_bounds__(256) void trimip_sample_sorted(
    const float* __restrict__ spos, const unsigned* __restrict__ sidx,
    const float* __restrict__ fm, const __half* __restrict__ pyr,
    float* __restrict__ out, int N)
{
    int tl = blockIdx.x * 256 + threadIdx.x;
    if (tl >= 2 * N) return;
    const int h = tl & 1;
    const int rank = tl >> 1;
    const int p = blockIdx.y;

    f4v sp = ld4(spos + (size_t)rank * 4);
    const unsigned n = sidx[rank];
    const float u = (p == 0) ? sp.y : sp.x;
    const float v = (p == 2) ? sp.y : sp.z;
    const float lv = sp.w;

    float lf = floorf(lv);
    float f = lv - lf;
    int l0 = (int)lf;
    int l1 = min(l0 + 1, 7);

    float s0[8], s1[8];
    if (l0 == 0) bilerp_l0(fm, p, u, v, h, s0);
    else         bilerp_h(pyr, p, l0, u, v, h, s0);
    bilerp_h(pyr, p, l1, u, v, h, s1);   // l1 >= 1 always

    float g = 1.f - f;
    f4v oa, ob;
    #pragma unroll
    for (int i = 0; i < 4; ++i) {
        oa[i] = s0[i] * g + s1[i] * f;
        ob[i] = s0[4 + i] * g + s1[4 + i] * f;
    }
    float* op = out + (size_t)n * 48 + p * 16 + h * 8;
    st4nt(op, oa);
    st4nt(op + 4, ob);
}

// ---------------- fp32 fallback path ----------------

__device__ __forceinline__ f4v avg4f(f4v a, f4v b, f4v c, f4v d) {
    return (a + b + c + d) * 0.25f;
}

__global__ __launch_bounds__(256) void mip_build_f(
    const float* __restrict__ src, float* __restrict__ dst)
{
    int t = blockIdx.x * blockDim.x + threadIdx.x;
    const int p = blockIdx.y;
    const int q = t & 3, idx = t >> 2;
    const int y = idx >> 8, x = idx & 255;
    const float* sp = src + (size_t)p * FM_PLANE_STRIDE
                          + ((size_t)(2 * y) * 512 + 2 * x) * 16 + q * 4;
    f4v r = avg4f(ld4(sp), ld4(sp + 16), ld4(sp + 512 * 16), ld4(sp + 512 * 16 + 16));
    st4(dst + (size_t)p * WS_PLANE_STRIDE + ((size_t)y * 256 + x) * 16 + q * 4, r);
}

__global__ __launch_bounds__(256) void mip_tail_f(float* __restrict__ mips)
{
    const int tile = blockIdx.x, q = blockIdx.y, p = blockIdx.z;
    const int ty = tile >> 2, tx = tile & 3;
    const int tid = threadIdx.x;
    __shared__ f4v A[32 * 32];
    __shared__ f4v B[16 * 16];
    float* plane = mips + (size_t)p * WS_PLANE_STRIDE;
    const float* L1 = plane;
    float* L2 = plane + (size_t)65536 * 16;
    float* L3 = plane + (size_t)81920 * 16;
    float* L4 = plane + (size_t)86016 * 16;
    float* L5 = plane + (size_t)87040 * 16;
    float* L6 = plane + (size_t)87296 * 16;
    float* L7 = plane + (size_t)87360 * 16;

    #pragma unroll
    for (int k = 0; k < 4; ++k) {
        int li = tid + k * 256;
        int ly = li >> 5, lx = li & 31;
        int gy = ty * 32 + ly, gx = tx * 32 + lx;
        const float* sp = L1 + ((size_t)(2 * gy) * 256 + 2 * gx) * 16 + q * 4;
        f4v r = avg4f(ld4(sp), ld4(sp + 16), ld4(sp + 256 * 16), ld4(sp + 256 * 16 + 16));
        A[li] = r;
        st4(L2 + ((size_t)gy * 128 + gx) * 16 + q * 4, r);
    }
    __syncthreads();
    {
        int ly = tid >> 4, lx = tid & 15;
        f4v r = avg4f(A[(2 * ly) * 32 + 2 * lx],     A[(2 * ly) * 32 + 2 * lx + 1],
                      A[(2 * ly + 1) * 32 + 2 * lx], A[(2 * ly + 1) * 32 + 2 * lx + 1]);
        B[tid] = r;
        st4(L3 + ((size_t)(ty * 16 + ly) * 64 + tx * 16 + lx) * 16 + q * 4, r);
    }
    __syncthreads();
    if (tid < 64) {
        int ly = tid >> 3, lx = tid & 7;
        f4v r = avg4f(B[(2 * ly) * 16 + 2 * lx],     B[(2 * ly) * 16 + 2 * lx + 1],
                      B[(2 * ly + 1) * 16 + 2 * lx], B[(2 * ly + 1) * 16 + 2 * lx + 1]);
        A[tid] = r;
        st4(L4 + ((size_t)(ty * 8 + ly) * 32 + tx * 8 + lx) * 16 + q * 4, r);
    }
    __syncthreads();
    if (tid < 16) {
        int ly = tid >> 2, lx = tid & 3;
        f4v r = avg4f(A[(2 * ly) * 8 + 2 * lx],     A[(2 * ly) * 8 + 2 * lx + 1],
                      A[(2 * ly + 1) * 8 + 2 * lx], A[(2 * ly + 1) * 8 + 2 * lx + 1]);
        B[tid] = r;
        st4(L5 + ((size_t)(ty * 4 + ly) * 16 + tx * 4 + lx) * 16 + q * 4, r);
    }
    __syncthreads();
    if (tid < 4) {
        int ly = tid >> 1, lx = tid & 1;
        f4v r = avg4f(B[(2 * ly) * 4 + 2 * lx],     B[(2 * ly) * 4 + 2 * lx + 1],
                      B[(2 * ly + 1) * 4 + 2 * lx], B[(2 * ly + 1) * 4 + 2 * lx + 1]);
        A[tid] = r;
        st4(L6 + ((size_t)(ty * 2 + ly) * 8 + tx * 2 + lx) * 16 + q * 4, r);
    }
    __syncthreads();
    if (tid == 0) {
        f4v r = avg4f(A[0], A[1], A[2], A[3]);
        st4(L7 + ((size_t)ty * 4 + tx) * 16 + q * 4, r);
    }
}

__device__ __forceinline__ f4v bilerp_f(
    const float* __restrict__ fm, const float* __restrict__ mips,
    int p, int l, float u, float v, int q)
{
    const int sz = 512 >> l;
    const float fsz = (float)sz;
    float px = u * fsz - 0.5f;
    float py = v * fsz - 0.5f;
    float xf = floorf(px), yf = floorf(py);
    float fx = px - xf, fy = py - yf;
    int xi = (int)xf, yi = (int)yf;
    int xa = min(max(xi, 0), sz - 1);
    int xb = min(xi + 1, sz - 1);
    int ya = min(max(yi, 0), sz - 1);
    int yb = min(yi + 1, sz - 1);
    const float* base;
    if (l == 0) {
        base = fm + (size_t)p * FM_PLANE_STRIDE;
    } else {
        unsigned off = (262144u - ((unsigned)(sz * sz) << 2)) / 3u;
        base = mips + (size_t)p * WS_PLANE_STRIDE + (size_t)off * 16;
    }
    const float* r0 = base + (size_t)(ya * sz) * 16 + q * 4;
    const float* r1 = base + (size_t)(yb * sz) * 16 + q * 4;
    f4v f00 = ld4(r0 + xa * 16);
    f4v f01 = ld4(r0 + xb * 16);
    f4v f10 = ld4(r1 + xa * 16);
    f4v f11 = ld4(r1 + xb * 16);
    float gx = 1.f - fx, gy = 1.f - fy;
    return (f00 * gx + f01 * fx) * gy + (f10 * gx + f11 * fx) * fy;
}

__global__ __launch_bounds__(256) void trimip_sample_f(
    const float* __restrict__ xyz, const float* __restrict__ level,
    const float* __restrict__ fm, const float* __restrict__ mips,
    float* __restrict__ out, int N)
{
    int t = blockIdx.x * blockDim.x + threadIdx.x;
    if (t >= N * 12) return;
    const int q = t & 3;
    const int r = t >> 2;
    const int n = r / 3;
    const int p = r - n * 3;
    const float c0 = xyz[n * 3 + 0];
    const float c1 = xyz[n * 3 + 1];
    const float c2 = xyz[n * 3 + 2];
    const float u = (p == 0) ? c1 : c0;
    const float v = (p == 2) ? c1 : c2;
    float lv = fminf(fmaxf(level[n], 0.f), 7.f);
    float lf = floorf(lv);
    float f = lv - lf;
    int l0 = (int)lf;
    int l1 = min(l0 + 1, 7);
    f4v s0 = bilerp_f(fm, mips, p, l0, u, v, q);
    f4v s1 = bilerp_f(fm, mips, p, l1, u, v, q);
    f4v o = s0 * (1.f - f) + s1 * f;
    st4nt(out + (size_t)t * 4, o);
}

extern "C" void kernel_launch(void* const* d_in, const int* in_sizes, int n_in,
                              void* d_out, int out_size, void* d_ws, size_t ws_size,
                              hipStream_t stream) {
    const float* xyz   = (const float*)d_in[0];
    const float* level = (const float*)d_in[1];
    const float* fm    = (const float*)d_in[2];
    float* out = (float*)d_out;
    const int N = in_sizes[1];

    const size_t sposOff = PYR_BYTES;
    const size_t sidxOff = sposOff + (size_t)N * 16;
    const size_t histOff = sidxOff + (size_t)N * 4;
    const size_t needed  = histOff + NBINS * 4;

    if (ws_size >= needed) {
        char* ws = (char*)d_ws;
        __half*   pyr  = (__half*)ws;
        float*    spos = (float*)(ws + sposOff);
        unsigned* sidx = (unsigned*)(ws + sidxOff);
        unsigned* hist = (unsigned*)(ws + histOff);
        const int nb = (N + 255) / 256;

        hipMemsetAsync(hist, 0, NBINS * 4, stream);
        mip_l1_h<<<dim3(1024, 3), dim3(256), 0, stream>>>(fm, pyr);
        mip_tail_h<<<dim3(16, 4, 3), dim3(256), 0, stream>>>(pyr);
        hist_build<<<nb, 256, 0, stream>>>(xyz, level, hist, N);
        scan_hist<<<1, 1024, 0, stream>>>(hist);
        scatter_pts<<<nb, 256, 0, stream>>>(xyz, level, hist, spos, sidx, N);
        trimip_sample_sorted<<<dim3((2 * N + 255) / 256, 3), dim3(256), 0, stream>>>(
            spos, sidx, fm, pyr, out, N);
    } else {
        float* mips = (float*)d_ws;
        mip_build_f<<<dim3(1024, 3), dim3(256), 0, stream>>>(fm, mips);
        mip_tail_f<<<dim3(16, 4, 3), dim3(256), 0, stream>>>(mips);
        trimip_sample_f<<<(N * 12 + 255) / 256, 256, 0, stream>>>(
            xyz, level, fm, mips, out, N);
    }
}

// Round 6
// 203.010 us; speedup vs baseline: 1.4223x; 1.4223x over previous
//
#include <hip/hip_runtime.h>
#include <hip/hip_fp16.h>

// TriMipEncoding: N pts, 3 planes (512^2, 16 ch), 8 mip levels, trilinear sample.
//
// Model (R3/R4/R5 evidence): sampler cost ~= 1 cycle per LANE-ADDRESS per CU,
// independent of bytes-from-HBM (R3: FETCH=0 same dur), line merging (R5:
// sorted lanes share lines, same dur), and which small level (R4). So:
// minimize lane-addresses. Texel gathers are minimal (16 B granularity);
// the waste was 6 threads/pt each re-loading xyz+level (24 addrs/pt).
// R6: block=384 = 64 pts; cooperative coalesced staging of {x,y,z,lvl}
// into LDS (4 addrs/pt), threads read via the free LDS pipe.
// Sort pipeline from R5 reverted (+80us overhead, zero gain).
//
// Fast path (ws_size >= 33.6 MB): full fp16 pyramid (levels 0..7) in d_ws.
//   Texel = 16 halfs = 32 B. off(l) = (2^20 - (2^20 >> 2l)) / 3 texels.
//   Plane stride = 349520 texels.

typedef float        f4v   __attribute__((ext_vector_type(4)));
typedef unsigned int u32x2 __attribute__((ext_vector_type(2)));

#define FM_PLANE_STRIDE (262144 * 16)   // floats per plane in fm
#define WS_PLANE_STRIDE (87376 * 16)    // floats per plane, fp32 fallback pyramid
#define PSTRIDE_H (349520 * 16)         // halfs per plane, fp16 full pyramid
#define WS_H_BYTES (3ull * PSTRIDE_H * 2ull)

__device__ __forceinline__ unsigned lvl_off(int l) {   // texel offset of level l
    return (1048576u - (1048576u >> (2 * l))) / 3u;
}

__device__ __forceinline__ f4v ld4(const float* p) {
    return *reinterpret_cast<const f4v*>(p);
}
__device__ __forceinline__ f4v ld4nt(const float* p) {
    return __builtin_nontemporal_load(reinterpret_cast<const f4v*>(p));
}
__device__ __forceinline__ void st4(float* p, f4v v) {
    *reinterpret_cast<f4v*>(p) = v;
}
__device__ __forceinline__ void st4nt(float* p, f4v v) {
    __builtin_nontemporal_store(v, reinterpret_cast<f4v*>(p));
}
__device__ __forceinline__ f4v ldraw_h(const __half* p) {   // 8 halfs as raw f4v
    return *reinterpret_cast<const f4v*>(p);
}
__device__ __forceinline__ u32x2 pack4(f4v v) {             // 4 floats -> 4 halfs
    __half2 lo = __floats2half2_rn(v.x, v.y);
    __half2 hi = __floats2half2_rn(v.z, v.w);
    u32x2 r;
    r.x = *reinterpret_cast<unsigned*>(&lo);
    r.y = *reinterpret_cast<unsigned*>(&hi);
    return r;
}
__device__ __forceinline__ f4v h4f(const __half* p) {       // 4 halfs -> 4 floats
    u32x2 u = *reinterpret_cast<const u32x2*>(p);
    unsigned a0 = u.x, a1 = u.y;
    __half2 lo = *reinterpret_cast<__half2*>(&a0);
    __half2 hi = *reinterpret_cast<__half2*>(&a1);
    float2 flo = __half22float2(lo), fhi = __half22float2(hi);
    f4v r; r.x = flo.x; r.y = flo.y; r.z = fhi.x; r.w = fhi.y;
    return r;
}
__device__ __forceinline__ float2 up2(float rawcomp) {      // 2 packed halfs -> 2 floats
    unsigned u = __float_as_uint(rawcomp);
    __half2 hh = *reinterpret_cast<__half2*>(&u);
    return __half22float2(hh);
}

// ---------------- fp16 path ----------------

// fm (fp32) -> L0' (fp16) + L1 (fp16). Thread per (L1 texel, quad q); grid (1024, 3).
__global__ __launch_bounds__(256) void mip_convert_l1(
    const float* __restrict__ fm, __half* __restrict__ wsh)
{
    int t = blockIdx.x * 256 + threadIdx.x;
    const int p = blockIdx.y;
    const int q = t & 3, idx = t >> 2;
    const int y = idx >> 8, x = idx & 255;
    const float* sp = fm + (size_t)p * FM_PLANE_STRIDE
                         + ((size_t)(2 * y) * 512 + 2 * x) * 16 + q * 4;
    f4v a = ld4nt(sp);
    f4v b = ld4nt(sp + 16);
    f4v c = ld4nt(sp + 512 * 16);
    f4v d = ld4nt(sp + 512 * 16 + 16);
    __half* L0 = wsh + (size_t)p * PSTRIDE_H;
    size_t o00 = ((size_t)(2 * y) * 512 + 2 * x) * 16 + q * 4;
    *reinterpret_cast<u32x2*>(L0 + o00)                 = pack4(a);
    *reinterpret_cast<u32x2*>(L0 + o00 + 16)            = pack4(b);
    *reinterpret_cast<u32x2*>(L0 + o00 + 512 * 16)      = pack4(c);
    *reinterpret_cast<u32x2*>(L0 + o00 + 512 * 16 + 16) = pack4(d);
    f4v m = (a + b + c + d) * 0.25f;   // L1 from fp32 source, single rounding
    __half* L1 = wsh + (size_t)p * PSTRIDE_H + (size_t)262144 * 16;
    *reinterpret_cast<u32x2*>(L1 + ((size_t)y * 256 + x) * 16 + q * 4) = pack4(m);
}

// Fused L2..L7 (fp16). Block = (32x32 L2 tile, quad q, plane p); grid (16,4,3).
__global__ __launch_bounds__(256) void mip_tail_h(__half* __restrict__ wsh)
{
    const int tile = blockIdx.x;
    const int q    = blockIdx.y;
    const int p    = blockIdx.z;
    const int ty = tile >> 2, tx = tile & 3;
    const int tid = threadIdx.x;

    __shared__ f4v A[32 * 32];
    __shared__ f4v B[16 * 16];

    __half* plane = wsh + (size_t)p * PSTRIDE_H;
    const __half* L1 = plane + (size_t)lvl_off(1) * 16;
    __half* L2 = plane + (size_t)lvl_off(2) * 16;
    __half* L3 = plane + (size_t)lvl_off(3) * 16;
    __half* L4 = plane + (size_t)lvl_off(4) * 16;
    __half* L5 = plane + (size_t)lvl_off(5) * 16;
    __half* L6 = plane + (size_t)lvl_off(6) * 16;
    __half* L7 = plane + (size_t)lvl_off(7) * 16;

    #pragma unroll
    for (int k = 0; k < 4; ++k) {
        int li = tid + k * 256;
        int ly = li >> 5, lx = li & 31;
        int gy = ty * 32 + ly, gx = tx * 32 + lx;
        const __half* sp = L1 + ((size_t)(2 * gy) * 256 + 2 * gx) * 16 + q * 4;
        f4v r = (h4f(sp) + h4f(sp + 16) + h4f(sp + 256 * 16) + h4f(sp + 256 * 16 + 16)) * 0.25f;
        A[li] = r;
        *reinterpret_cast<u32x2*>(L2 + ((size_t)gy * 128 + gx) * 16 + q * 4) = pack4(r);
    }
    __syncthreads();

    {   // L3: 16x16
        int ly = tid >> 4, lx = tid & 15;
        f4v r = (A[(2 * ly) * 32 + 2 * lx]     + A[(2 * ly) * 32 + 2 * lx + 1] +
                 A[(2 * ly + 1) * 32 + 2 * lx] + A[(2 * ly + 1) * 32 + 2 * lx + 1]) * 0.25f;
        B[tid] = r;
        *reinterpret_cast<u32x2*>(L3 + ((size_t)(ty * 16 + ly) * 64 + tx * 16 + lx) * 16 + q * 4) = pack4(r);
    }
    __syncthreads();

    if (tid < 64) {   // L4: 8x8
        int ly = tid >> 3, lx = tid & 7;
        f4v r = (B[(2 * ly) * 16 + 2 * lx]     + B[(2 * ly) * 16 + 2 * lx + 1] +
                 B[(2 * ly + 1) * 16 + 2 * lx] + B[(2 * ly + 1) * 16 + 2 * lx + 1]) * 0.25f;
        A[tid] = r;
        *reinterpret_cast<u32x2*>(L4 + ((size_t)(ty * 8 + ly) * 32 + tx * 8 + lx) * 16 + q * 4) = pack4(r);
    }
    __syncthreads();

    if (tid < 16) {   // L5: 4x4
        int ly = tid >> 2, lx = tid & 3;
        f4v r = (A[(2 * ly) * 8 + 2 * lx]     + A[(2 * ly) * 8 + 2 * lx + 1] +
                 A[(2 * ly + 1) * 8 + 2 * lx] + A[(2 * ly + 1) * 8 + 2 * lx + 1]) * 0.25f;
        B[tid] = r;
        *reinterpret_cast<u32x2*>(L5 + ((size_t)(ty * 4 + ly) * 16 + tx * 4 + lx) * 16 + q * 4) = pack4(r);
    }
    __syncthreads();

    if (tid < 4) {    // L6: 2x2
        int ly = tid >> 1, lx = tid & 1;
        f4v r = (B[(2 * ly) * 4 + 2 * lx]     + B[(2 * ly) * 4 + 2 * lx + 1] +
                 B[(2 * ly + 1) * 4 + 2 * lx] + B[(2 * ly + 1) * 4 + 2 * lx + 1]) * 0.25f;
        A[tid] = r;
        *reinterpret_cast<u32x2*>(L6 + ((size_t)(ty * 2 + ly) * 8 + tx * 2 + lx) * 16 + q * 4) = pack4(r);
    }
    __syncthreads();

    if (tid == 0) {   // L7: 1 texel
        f4v r = (A[0] + A[1] + A[2] + A[3]) * 0.25f;
        *reinterpret_cast<u32x2*>(L7 + ((size_t)ty * 4 + tx) * 16 + q * 4) = pack4(r);
    }
}

// Weighted 8-channel bilinear tap from the fp16 pyramid.
__device__ __forceinline__ void bilerp8(
    const __half* __restrict__ wsh, int p, int l, float u, float v, int h, float* o)
{
    const int sz = 512 >> l;
    const float fsz = (float)sz;
    float px = u * fsz - 0.5f;
    float py = v * fsz - 0.5f;
    float xf = floorf(px), yf = floorf(py);
    float fx = px - xf, fy = py - yf;
    int xi = (int)xf, yi = (int)yf;
    int xa = min(max(xi, 0), sz - 1);
    int xb = min(xi + 1, sz - 1);      // xi >= -1 always
    int ya = min(max(yi, 0), sz - 1);
    int yb = min(yi + 1, sz - 1);
    const __half* base = wsh + (size_t)p * PSTRIDE_H + (size_t)lvl_off(l) * 16 + h * 8;
    const __half* r0 = base + (size_t)(ya * sz) * 16;
    const __half* r1 = base + (size_t)(yb * sz) * 16;
    f4v q00 = ldraw_h(r0 + (size_t)xa * 16);
    f4v q01 = ldraw_h(r0 + (size_t)xb * 16);
    f4v q10 = ldraw_h(r1 + (size_t)xa * 16);
    f4v q11 = ldraw_h(r1 + (size_t)xb * 16);
    float gx = 1.f - fx, gy = 1.f - fy;
    float w00 = gx * gy, w01 = fx * gy, w10 = gx * fy, w11 = fx * fy;
    #pragma unroll
    for (int i = 0; i < 4; ++i) {
        float2 a = up2(q00[i]), b = up2(q01[i]), c = up2(q10[i]), d = up2(q11[i]);
        o[2 * i]     = a.x * w00 + b.x * w01 + c.x * w10 + d.x * w11;
        o[2 * i + 1] = a.y * w00 + b.y * w01 + c.y * w10 + d.y * w11;
    }
}

// Block = 384 threads = 64 points x 6 (plane p, half h).
// Stage {x,y,z,lvl} for the block's 64 points into LDS with 256 coalesced
// dword loads, then all threads read point data from LDS (free pipe).
__global__ __launch_bounds__(384) void trimip_sample_h(
    const float* __restrict__ xyz, const float* __restrict__ level,
    const __half* __restrict__ wsh, float* __restrict__ out, int N)
{
    __shared__ float pt[64 * 4];      // x, y, z, lvl per point
    const int tid = threadIdx.x;
    const int nbase = blockIdx.x * 64;

    if (tid < 192) {                  // 64 pts * 3 coords, coalesced
        int j = tid;
        if (nbase * 3 + j < N * 3) {
            int n_l = j / 3, c = j - n_l * 3;
            pt[n_l * 4 + c] = xyz[(size_t)nbase * 3 + j];
        }
    } else if (tid < 256) {           // 64 levels
        int j = tid - 192;
        if (nbase + j < N) {
            float lv = level[nbase + j];
            pt[j * 4 + 3] = fminf(fmaxf(lv, 0.f), 7.f);
        }
    }
    __syncthreads();

    const int n_l = tid / 6;
    const int rem = tid - n_l * 6;
    const int n = nbase + n_l;
    if (n_l >= 64 || n >= N) return;
    const int p = rem >> 1;
    const int h = rem & 1;

    const float x  = pt[n_l * 4 + 0];
    const float y  = pt[n_l * 4 + 1];
    const float z  = pt[n_l * 4 + 2];
    const float lv = pt[n_l * 4 + 3];
    const float u = (p == 0) ? y : x;
    const float v = (p == 2) ? y : z;

    float lf = floorf(lv);
    float f = lv - lf;
    int l0 = (int)lf;
    int l1 = min(l0 + 1, 7);

    float s0[8], s1[8];
    bilerp8(wsh, p, l0, u, v, h, s0);
    bilerp8(wsh, p, l1, u, v, h, s1);
    float g = 1.f - f;
    f4v oa, ob;
    #pragma unroll
    for (int i = 0; i < 4; ++i) {
        oa[i] = s0[i] * g + s1[i] * f;
        ob[i] = s0[4 + i] * g + s1[4 + i] * f;
    }
    float* op = out + (size_t)n * 48 + p * 16 + h * 8;
    st4nt(op, oa);
    st4nt(op + 4, ob);
}

// ---------------- fp32 fallback path ----------------

__device__ __forceinline__ f4v avg4f(f4v a, f4v b, f4v c, f4v d) {
    return (a + b + c + d) * 0.25f;
}

__global__ __launch_bounds__(256) void mip_build_f(
    const float* __restrict__ src, float* __restrict__ dst)
{
    int t = blockIdx.x * blockDim.x + threadIdx.x;
    const int p = blockIdx.y;
    const int q = t & 3, idx = t >> 2;
    const int y = idx >> 8, x = idx & 255;
    const float* sp = src + (size_t)p * FM_PLANE_STRIDE
                          + ((size_t)(2 * y) * 512 + 2 * x) * 16 + q * 4;
    f4v r = avg4f(ld4(sp), ld4(sp + 16), ld4(sp + 512 * 16), ld4(sp + 512 * 16 + 16));
    st4(dst + (size_t)p * WS_PLANE_STRIDE + ((size_t)y * 256 + x) * 16 + q * 4, r);
}

__global__ __launch_bounds__(256) void mip_tail_f(float* __restrict__ mips)
{
    const int tile = blockIdx.x, q = blockIdx.y, p = blockIdx.z;
    const int ty = tile >> 2, tx = tile & 3;
    const int tid = threadIdx.x;
    __shared__ f4v A[32 * 32];
    __shared__ f4v B[16 * 16];
    float* plane = mips + (size_t)p * WS_PLANE_STRIDE;
    const float* L1 = plane;
    float* L2 = plane + (size_t)65536 * 16;
    float* L3 = plane + (size_t)81920 * 16;
    float* L4 = plane + (size_t)86016 * 16;
    float* L5 = plane + (size_t)87040 * 16;
    float* L6 = plane + (size_t)87296 * 16;
    float* L7 = plane + (size_t)87360 * 16;

    #pragma unroll
    for (int k = 0; k < 4; ++k) {
        int li = tid + k * 256;
        int ly = li >> 5, lx = li & 31;
        int gy = ty * 32 + ly, gx = tx * 32 + lx;
        const float* sp = L1 + ((size_t)(2 * gy) * 256 + 2 * gx) * 16 + q * 4;
        f4v r = avg4f(ld4(sp), ld4(sp + 16), ld4(sp + 256 * 16), ld4(sp + 256 * 16 + 16));
        A[li] = r;
        st4(L2 + ((size_t)gy * 128 + gx) * 16 + q * 4, r);
    }
    __syncthreads();
    {
        int ly = tid >> 4, lx = tid & 15;
        f4v r = avg4f(A[(2 * ly) * 32 + 2 * lx],     A[(2 * ly) * 32 + 2 * lx + 1],
                      A[(2 * ly + 1) * 32 + 2 * lx], A[(2 * ly + 1) * 32 + 2 * lx + 1]);
        B[tid] = r;
        st4(L3 + ((size_t)(ty * 16 + ly) * 64 + tx * 16 + lx) * 16 + q * 4, r);
    }
    __syncthreads();
    if (tid < 64) {
        int ly = tid >> 3, lx = tid & 7;
        f4v r = avg4f(B[(2 * ly) * 16 + 2 * lx],     B[(2 * ly) * 16 + 2 * lx + 1],
                      B[(2 * ly + 1) * 16 + 2 * lx], B[(2 * ly + 1) * 16 + 2 * lx + 1]);
        A[tid] = r;
        st4(L4 + ((size_t)(ty * 8 + ly) * 32 + tx * 8 + lx) * 16 + q * 4, r);
    }
    __syncthreads();
    if (tid < 16) {
        int ly = tid >> 2, lx = tid & 3;
        f4v r = avg4f(A[(2 * ly) * 8 + 2 * lx],     A[(2 * ly) * 8 + 2 * lx + 1],
                      A[(2 * ly + 1) * 8 + 2 * lx], A[(2 * ly + 1) * 8 + 2 * lx + 1]);
        B[tid] = r;
        st4(L5 + ((size_t)(ty * 4 + ly) * 16 + tx * 4 + lx) * 16 + q * 4, r);
    }
    __syncthreads();
    if (tid < 4) {
        int ly = tid >> 1, lx = tid & 1;
        f4v r = avg4f(B[(2 * ly) * 4 + 2 * lx],     B[(2 * ly) * 4 + 2 * lx + 1],
                      B[(2 * ly + 1) * 4 + 2 * lx], B[(2 * ly + 1) * 4 + 2 * lx + 1]);
        A[tid] = r;
        st4(L6 + ((size_t)(ty * 2 + ly) * 8 + tx * 2 + lx) * 16 + q * 4, r);
    }
    __syncthreads();
    if (tid == 0) {
        f4v r = avg4f(A[0], A[1], A[2], A[3]);
        st4(L7 + ((size_t)ty * 4 + tx) * 16 + q * 4, r);
    }
}

__device__ __forceinline__ f4v bilerp_f(
    const float* __restrict__ fm, const float* __restrict__ mips,
    int p, int l, float u, float v, int q)
{
    const int sz = 512 >> l;
    const float fsz = (float)sz;
    float px = u * fsz - 0.5f;
    float py = v * fsz - 0.5f;
    float xf = floorf(px), yf = floorf(py);
    float fx = px - xf, fy = py - yf;
    int xi = (int)xf, yi = (int)yf;
    int xa = min(max(xi, 0), sz - 1);
    int xb = min(xi + 1, sz - 1);
    int ya = min(max(yi, 0), sz - 1);
    int yb = min(yi + 1, sz - 1);
    const float* base;
    if (l == 0) {
        base = fm + (size_t)p * FM_PLANE_STRIDE;
    } else {
        unsigned off = (262144u - ((unsigned)(sz * sz) << 2)) / 3u;
        base = mips + (size_t)p * WS_PLANE_STRIDE + (size_t)off * 16;
    }
    const float* r0 = base + (size_t)(ya * sz) * 16 + q * 4;
    const float* r1 = base + (size_t)(yb * sz) * 16 + q * 4;
    f4v f00 = ld4(r0 + xa * 16);
    f4v f01 = ld4(r0 + xb * 16);
    f4v f10 = ld4(r1 + xa * 16);
    f4v f11 = ld4(r1 + xb * 16);
    float gx = 1.f - fx, gy = 1.f - fy;
    return (f00 * gx + f01 * fx) * gy + (f10 * gx + f11 * fx) * fy;
}

__global__ __launch_bounds__(256) void trimip_sample_f(
    const float* __restrict__ xyz, const float* __restrict__ level,
    const float* __restrict__ fm, const float* __restrict__ mips,
    float* __restrict__ out, int N)
{
    int t = blockIdx.x * blockDim.x + threadIdx.x;
    if (t >= N * 12) return;
    const int q = t & 3;
    const int r = t >> 2;
    const int n = r / 3;
    const int p = r - n * 3;
    const float c0 = xyz[n * 3 + 0];
    const float c1 = xyz[n * 3 + 1];
    const float c2 = xyz[n * 3 + 2];
    const float u = (p == 0) ? c1 : c0;
    const float v = (p == 2) ? c1 : c2;
    float lv = fminf(fmaxf(level[n], 0.f), 7.f);
    float lf = floorf(lv);
    float f = lv - lf;
    int l0 = (int)lf;
    int l1 = min(l0 + 1, 7);
    f4v s0 = bilerp_f(fm, mips, p, l0, u, v, q);
    f4v s1 = bilerp_f(fm, mips, p, l1, u, v, q);
    f4v o = s0 * (1.f - f) + s1 * f;
    st4nt(out + (size_t)t * 4, o);
}

extern "C" void kernel_launch(void* const* d_in, const int* in_sizes, int n_in,
                              void* d_out, int out_size, void* d_ws, size_t ws_size,
                              hipStream_t stream) {
    const float* xyz   = (const float*)d_in[0];
    const float* level = (const float*)d_in[1];
    const float* fm    = (const float*)d_in[2];
    float* out = (float*)d_out;
    const int N = in_sizes[1];

    if (ws_size >= WS_H_BYTES) {
        __half* wsh = (__half*)d_ws;
        mip_convert_l1<<<dim3(1024, 3), dim3(256), 0, stream>>>(fm, wsh);
        mip_tail_h<<<dim3(16, 4, 3), dim3(256), 0, stream>>>(wsh);
        const int nblocks = (N + 63) / 64;          // 64 points per block
        trimip_sample_h<<<nblocks, 384, 0, stream>>>(xyz, level, wsh, out, N);
    } else {
        float* mips = (float*)d_ws;
        mip_build_f<<<dim3(1024, 3), dim3(256), 0, stream>>>(fm, mips);
        mip_tail_f<<<dim3(16, 4, 3), dim3(256), 0, stream>>>(mips);
        trimip_sample_f<<<(N * 12 + 255) / 256, 256, 0, stream>>>(
            xyz, level, fm, mips, out, N);
    }
}